// Round 3
// baseline (146.570 us; speedup 1.0000x reference)
//
#include <hip/hip_runtime.h>
#include <hip/hip_bf16.h>

// ProtoNet LOO loss on MI355X — round 3.
// logit[q,k] = xq·p[k] - 0.5||p[k]||^2 - 0.5||xq||^2 (non-LOO) with closed-form
// leave-one-out fixup for k* = ys[pos[q]].
// R3: loss QB=8 + float4-packed pTv (coalesced 16B/lane loads, L2 traffic
// halved, FMA-issue-bound); proto float4 gathers (16 groups x 32 f4-lanes,
// 8-deep ILP); bucket int4.

#define NQ_ 2048
#define NS_ 65536
#define K_  512
#define D_  128
#define CAP_ 160   // per-class row-list capacity (actual count is exactly 128)
#define QB_ 8      // queries per block in the loss kernel

// ---------------------------------------------------------------- bucket ----
__global__ void bucket_kernel(const int* __restrict__ ys,
                              int* __restrict__ counts,
                              int* __restrict__ list) {
    int i = blockIdx.x * blockDim.x + threadIdx.x;   // 0..16383
    int4 y = ((const int4*)ys)[i];
    int s = i * 4;
    int c, slot;
    c = y.x; slot = atomicAdd(&counts[c], 1); if (slot < CAP_) list[c * CAP_ + slot] = s + 0;
    c = y.y; slot = atomicAdd(&counts[c], 1); if (slot < CAP_) list[c * CAP_ + slot] = s + 1;
    c = y.z; slot = atomicAdd(&counts[c], 1); if (slot < CAP_) list[c * CAP_ + slot] = s + 2;
    c = y.w; slot = atomicAdd(&counts[c], 1); if (slot < CAP_) list[c * CAP_ + slot] = s + 3;
}

// ----------------------------------------------------------------- proto ----
// One block (512 threads = 8 waves) per class. 16 row-groups x 32 float4
// lanes; float4 gathers with 8-deep ILP. Writes pTv (float4-packed transposed
// prototypes: float4 element index d4*K_+k) and pnorm[k] = ||p[k]||^2.
__global__ void proto_kernel(const float* __restrict__ xs,
                             const int* __restrict__ counts,
                             const int* __restrict__ list,
                             float* __restrict__ pTv,
                             float* __restrict__ pnorm) {
    int k  = blockIdx.x;
    int t  = threadIdx.x;          // 0..511
    int d4 = t & 31;               // float4 index 0..31
    int h  = t >> 5;               // row-group 0..15
    __shared__ int   idx_s[CAP_];
    __shared__ float part_s[16 * 128];   // 8 KB
    __shared__ float red_s[2];

    int cnt = counts[k];
    int m = min(cnt, CAP_);
    if (t < CAP_) idx_s[t] = (t < m) ? list[k * CAP_ + t] : 0;
    __syncthreads();

    const float4* xs4 = (const float4*)xs;
    int r0 = (m * h) >> 4, r1 = (m * (h + 1)) >> 4;
    float4 acc = make_float4(0.f, 0.f, 0.f, 0.f);
    int r = r0;
    for (; r + 8 <= r1; r += 8) {        // 8 independent 16B gathers in flight
        float4 v0 = xs4[idx_s[r+0] * 32 + d4];
        float4 v1 = xs4[idx_s[r+1] * 32 + d4];
        float4 v2 = xs4[idx_s[r+2] * 32 + d4];
        float4 v3 = xs4[idx_s[r+3] * 32 + d4];
        float4 v4 = xs4[idx_s[r+4] * 32 + d4];
        float4 v5 = xs4[idx_s[r+5] * 32 + d4];
        float4 v6 = xs4[idx_s[r+6] * 32 + d4];
        float4 v7 = xs4[idx_s[r+7] * 32 + d4];
        acc.x += ((v0.x+v1.x)+(v2.x+v3.x)) + ((v4.x+v5.x)+(v6.x+v7.x));
        acc.y += ((v0.y+v1.y)+(v2.y+v3.y)) + ((v4.y+v5.y)+(v6.y+v7.y));
        acc.z += ((v0.z+v1.z)+(v2.z+v3.z)) + ((v4.z+v5.z)+(v6.z+v7.z));
        acc.w += ((v0.w+v1.w)+(v2.w+v3.w)) + ((v4.w+v5.w)+(v6.w+v7.w));
    }
    for (; r < r1; ++r) {
        float4 v = xs4[idx_s[r] * 32 + d4];
        acc.x += v.x; acc.y += v.y; acc.z += v.z; acc.w += v.w;
    }
    *(float4*)&part_s[h * 128 + d4 * 4] = acc;
    __syncthreads();

    if (t < 128) {
        int d = t;
        float s = 0.f;
        #pragma unroll
        for (int g = 0; g < 16; ++g) s += part_s[g * 128 + d];
        float pv = s / fmaxf((float)cnt, 0.1f);
        // float4-packed transposed store: component (d&3) of pTv[(d>>2)*K_+k]
        pTv[(d >> 2) * (K_ * 4) + (k << 2) + (d & 3)] = pv;
        float sq = pv * pv;
        #pragma unroll
        for (int off = 32; off; off >>= 1) sq += __shfl_down(sq, off, 64);
        if ((d & 63) == 0) red_s[d >> 6] = sq;
    }
    __syncthreads();
    if (t == 0) pnorm[k] = red_s[0] + red_s[1];
}

// ------------------------------------------------------------------ loss ----
__device__ inline float logit_of(float dot, float pn, float cnt, float qn, bool loo) {
    if (!loo) {
        if (cnt <= 0.1f) return 0.f;              // mask (C = cnt)
        return dot - 0.5f * pn - 0.5f * qn;
    }
    float cm1 = cnt - 1.f;
    if (cm1 <= 0.1f) return 0.f;                  // mask (C = cnt-1)
    float dotM = cnt * dot;                        // xq·mus
    float msq  = cnt * cnt * pn;                   // ||mus||^2
    float xp   = (dotM - qn) / cm1;                // xq·p_loo
    float plsq = (msq - 2.f * dotM + qn) / (cm1 * cm1);
    return xp - 0.5f * plsq - 0.5f * qn;
}

__launch_bounds__(512)
__global__ void loss_kernel(const float* __restrict__ xq,
                            const int* __restrict__ ys,
                            const int* __restrict__ pos,
                            const float* __restrict__ pTv,
                            const float* __restrict__ pnorm,
                            const int* __restrict__ counts,
                            float* __restrict__ out) {
    __shared__ float xq_s[QB_ * D_];        // 4 KB
    __shared__ float logit_s[QB_][K_];      // 16 KB
    __shared__ float qn_s[QB_];
    __shared__ int   ks_s[QB_];

    int t    = threadIdx.x;                 // 0..511; t == class id
    int wave = t >> 6, lane = t & 63;
    int q0   = blockIdx.x * QB_;

    // stage xq tile (8 rows x 128 f32 = 256 float4) + fused ||xq||^2
    if (t < 256) {
        float4 v = ((const float4*)(xq + q0 * D_))[t];
        *(float4*)&xq_s[t * 4] = v;
        float s = v.x*v.x + v.y*v.y + v.z*v.z + v.w*v.w;
        #pragma unroll
        for (int off = 16; off; off >>= 1) s += __shfl_down(s, off, 32);
        if ((t & 31) == 0) qn_s[t >> 5] = s;
    }
    if (t < QB_) ks_s[t] = ys[pos[q0 + t]];
    __syncthreads();

    // dot(xq[q], p[k]) for k = t, q = q0..q0+7.
    // pTv: float4 element d4*K_+k -> 16B/lane fully-coalesced wave loads.
    // xq via ds_read_b128 broadcast (same address all lanes = conflict-free).
    float acc[QB_];
    #pragma unroll
    for (int q = 0; q < QB_; ++q) acc[q] = 0.f;
    const float4* p4 = (const float4*)pTv;
    #pragma unroll 4
    for (int d4 = 0; d4 < D_ / 4; ++d4) {
        float4 pa = p4[d4 * K_ + t];
        #pragma unroll
        for (int q = 0; q < QB_; ++q) {
            float4 xv = *(const float4*)&xq_s[q * D_ + d4 * 4];
            acc[q] = fmaf(pa.x, xv.x, acc[q]);
            acc[q] = fmaf(pa.y, xv.y, acc[q]);
            acc[q] = fmaf(pa.z, xv.z, acc[q]);
            acc[q] = fmaf(pa.w, xv.w, acc[q]);
        }
    }

    float pn = pnorm[t];
    float cf = (float)counts[t];
    #pragma unroll
    for (int q = 0; q < QB_; ++q)
        logit_s[q][t] = logit_of(acc[q], pn, cf, qn_s[q], t == ks_s[q]);
    __syncthreads();

    // softmax + NLL: wave w handles query q0+w over 512 logits
    {
        int q = wave;
        float vals[8];
        float vmax = -1e30f;
        #pragma unroll
        for (int j = 0; j < 8; ++j) {
            vals[j] = logit_s[q][lane + j * 64];
            vmax = fmaxf(vmax, vals[j]);
        }
        #pragma unroll
        for (int off = 32; off; off >>= 1) vmax = fmaxf(vmax, __shfl_xor(vmax, off, 64));
        float se = 0.f;
        #pragma unroll
        for (int j = 0; j < 8; ++j) se += __expf(vals[j] - vmax);
        #pragma unroll
        for (int off = 32; off; off >>= 1) se += __shfl_xor(se, off, 64);
        if (lane == 0) {
            float lse = vmax + __logf(se);        // T = 1.0
            float lk  = logit_s[q][ks_s[q]];
            atomicAdd(out, (lse - lk) * (1.0f / NQ_));
        }
    }
}

// ---------------------------------------------------------------- launch ----
extern "C" void kernel_launch(void* const* d_in, const int* in_sizes, int n_in,
                              void* d_out, int out_size, void* d_ws, size_t ws_size,
                              hipStream_t stream) {
    const float* xq  = (const float*)d_in[0];
    // d_in[1] = yq (unused beyond its length)
    const float* xs  = (const float*)d_in[2];
    const int*   ys  = (const int*)d_in[3];
    const int*   pos = (const int*)d_in[4];
    float* out = (float*)d_out;

    char* ws = (char*)d_ws;
    int*   counts = (int*)ws;                                   // K_ ints
    int*   list   = (int*)(ws + 4096);                          // K_*CAP_ ints
    float* pTv    = (float*)(ws + 4096 + K_*CAP_*4);            // D_*K_ f32, f4-packed
    float* pnorm  = (float*)(ws + 4096 + K_*CAP_*4 + K_*D_*4);  // K_ f32

    hipMemsetAsync(counts, 0, K_ * sizeof(int), stream);
    hipMemsetAsync(out, 0, sizeof(float), stream);

    bucket_kernel<<<NS_ / (256 * 4), 256, 0, stream>>>(ys, counts, list);
    proto_kernel<<<K_, 512, 0, stream>>>(xs, counts, list, pTv, pnorm);
    loss_kernel<<<NQ_ / QB_, 512, 0, stream>>>(xq, ys, pos, pTv, pnorm, counts, out);
}